// Round 5
// baseline (224.527 us; speedup 1.0000x reference)
//
#include <hip/hip_runtime.h>
#include <math.h>

// Problem constants
#define HH 512
#define WW 512
#define NB 64
#define CXY 56          // crop offset of Xc in x
#define TOFF 66         // crop offset of tmpl in template (MS+C = 10+56)
#define TN 380          // template side
#define XN 400          // cropped image side
#define NL 21           // number of lags per dim (XN-TN+1)
#define N_T 144400.0f   // TN*TN
#define EPSF 1e-8f
#define NUT 24          // u-tiles of 16 rows (24*16 = 384 >= 380)

// d_ws float offsets
#define TPART_S   0                    // 380
#define TPART_S2  384                  // 380
#define TSTATS    768                  // [0]=mu_t [1]=t_var
#define ROWSUM    1024                 // 64*400*21 = 537600
#define ROWSUMSQ  (ROWSUM + 537600)    // 538624
#define LOCALSUM  (ROWSUMSQ + 537600)  // 1076224 (64*441)
#define LOCALSQ   (LOCALSUM + 28224)   // 1104448
#define CCPART2   (LOCALSQ + 28224)    // 1132672 (64*24*441 = 677376)
#define SHIFTS    (CCPART2 + 677376)   // 1810048 (final float shifts)
#define SHIFTSI   (SHIFTS + 128)       // integer argmax cells
#define EXACTN    (SHIFTSI + 128)      // exact numerators, 5/batch
#define TSHIFT_F  (EXACTN + 384)       // 1810688; f16 buffer 21*384*416 halfs

typedef _Float16 half2_t __attribute__((ext_vector_type(2)));
typedef _Float16 f16x8 __attribute__((ext_vector_type(8)));
typedef float f32x4 __attribute__((ext_vector_type(4)));

// ---------------- K0a: per-template-row partial sums ----------------
__global__ __launch_bounds__(128) void k_tstats1(const float* __restrict__ tpl,
                                                 float* __restrict__ ws) {
    int u = blockIdx.x;            // 0..379
    int l = threadIdx.x;           // 128
    const float* row = tpl + (TOFF + u) * WW + TOFF;
    float s = 0.f, s2 = 0.f;
    for (int v = l; v < TN; v += 128) { float t = row[v]; s += t; s2 += t * t; }
    for (int off = 32; off; off >>= 1) { s += __shfl_down(s, off); s2 += __shfl_down(s2, off); }
    __shared__ float rs[2], rs2[2];
    int wid = l >> 6;
    if ((l & 63) == 0) { rs[wid] = s; rs2[wid] = s2; }
    __syncthreads();
    if (l == 0) { ws[TPART_S + u] = rs[0] + rs[1]; ws[TPART_S2 + u] = rs2[0] + rs2[1]; }
}

// ---------------- K0b: finalize template stats ----------------
__global__ __launch_bounds__(512) void k_tstats2(float* __restrict__ ws) {
    int l = threadIdx.x;           // 512
    float s  = (l < TN) ? ws[TPART_S + l]  : 0.f;
    float s2 = (l < TN) ? ws[TPART_S2 + l] : 0.f;
    for (int off = 32; off; off >>= 1) { s += __shfl_down(s, off); s2 += __shfl_down(s2, off); }
    __shared__ float rs[8], rs2[8];
    int wid = l >> 6;
    if ((l & 63) == 0) { rs[wid] = s; rs2[wid] = s2; }
    __syncthreads();
    if (l == 0) {
        float S = 0.f, S2 = 0.f;
        for (int k = 0; k < 8; ++k) { S += rs[k]; S2 += rs2[k]; }
        float mu = S / N_T;
        ws[TSTATS] = mu;
        ws[TSTATS + 1] = S2 - S * mu + EPSF;   // sum((T-mu)^2) + EPS
    }
}

// ---------------- K0c: build 21 shifted zero-mean f16 template copies ----------------
// T_j[u][v'] = (u<380 && 0 <= v'-j < 380) ? tpl[u][v'-j]-mu : 0, u in [0,384), v' in [0,416)
__global__ __launch_bounds__(256) void k_tshift(const float* __restrict__ tpl,
                                                float* __restrict__ ws) {
    int u = blockIdx.x;            // 0..383
    int j = blockIdx.y;            // 0..20
    float mu = ws[TSTATS];
    _Float16* dst = (_Float16*)(ws + TSHIFT_F) + ((size_t)j * 384 + u) * 416;
    for (int c = threadIdx.x; c < 416; c += 256) {
        float v = 0.f;
        int vs = c - j;
        if (u < TN && vs >= 0 && vs < TN) v = tpl[(TOFF + u) * WW + TOFF + vs] - mu;
        dst[c] = (_Float16)v;
    }
}

// ---------------- K1: per-row 380-wide sliding window sums ----------------
__global__ __launch_bounds__(256) void k_rowsum(const float* __restrict__ x,
                                                float* __restrict__ ws) {
    __shared__ float sm[4][XN];
    int wid = threadIdx.x >> 6, lane = threadIdx.x & 63;
    int row = blockIdx.x * 4 + wid;        // 0..25599
    int b = row / XN, p = row % XN;
    const float* xr = x + ((size_t)b * HH + (CXY + p)) * WW + CXY;
    float s = 0.f, s2 = 0.f;
    for (int v = lane; v < XN; v += 64) {
        float t = xr[v];
        sm[wid][v] = t;
        if (v < TN) { s += t; s2 += t * t; }
    }
    for (int off = 32; off; off >>= 1) { s += __shfl_down(s, off); s2 += __shfl_down(s2, off); }
    __syncthreads();
    if (lane == 0) {
        float* rs  = ws + ROWSUM   + (size_t)row * NL;
        float* rq  = ws + ROWSUMSQ + (size_t)row * NL;
        float w = s, w2 = s2;
        rs[0] = w; rq[0] = w2;
        for (int j = 1; j < NL; ++j) {
            float a = sm[wid][j - 1], bv = sm[wid][j + TN - 1];
            w  += bv - a;
            w2 += bv * bv - a * a;
            rs[j] = w; rq[j] = w2;
        }
    }
}

// ---------------- K2: vertical 380-tall sums -> localsum / localsum_sq ----------------
__global__ __launch_bounds__(512) void k_vert(float* __restrict__ ws) {
    int b = blockIdx.x, t = threadIdx.x;
    __shared__ float sm[XN * NL];   // 8400 floats = 33.6KB
    for (int k = t; k < XN * NL; k += 512) sm[k] = ws[ROWSUM + (size_t)b * (XN * NL) + k];
    __syncthreads();
    if (t < NL * NL) {
        float s = 0.f;
        for (int p = 0; p < TN; ++p) s += sm[t + p * NL];
        ws[LOCALSUM + b * (NL * NL) + t] = s;
    }
    __syncthreads();
    for (int k = t; k < XN * NL; k += 512) sm[k] = ws[ROWSUMSQ + (size_t)b * (XN * NL) + k];
    __syncthreads();
    if (t < NL * NL) {
        float s = 0.f;
        for (int p = 0; p < TN; ++p) s += sm[t + p * NL];
        ws[LOCALSQ + b * (NL * NL) + t] = s;
    }
}

// ---------------- K3: MFMA cross-correlation ----------------
// Block = (batch, u-tile of 16 T rows). GEMM per j: D[u][w] = sum_v' T_j[u][v'] X[w][v'],
// M=16 (u), N=48 (w in [U,U+48)), K=416 (13 chunks of 32), mfma_f32_16x16x32_f16.
// 4 waves split the 21 j's (wave wv: j = wv+4*jj). X tile staged once in LDS (f16),
// A-frags read from global T_j (L2-resident, shared across batches).
// Band extract: cc[i][j] += D[u][u+i] via per-wave LDS scratch.
__global__ __launch_bounds__(256) void k_ccm(const float* __restrict__ x,
                                             float* __restrict__ ws) {
    const int b = blockIdx.x, Ut = blockIdx.y;
    const int U = Ut * 16;
    const int tid = threadIdx.x;
    const int lane = tid & 63, wv = tid >> 6;
    __shared__ __align__(16) _Float16 sX[48 * 416];   // 39936 B
    __shared__ float sD[4][16][50];                   // 12800 B (50: pad vs 4-way write conflict)

    // ---- stage X rows [U, U+48), cols [CXY, CXY+416) as f16 (all in-bounds: <=471 < 512) ----
    {
        const float* base = x + (size_t)b * (HH * WW);
        for (int rr = 0; rr < 12; ++rr) {
            int r = wv * 12 + rr;
            const float* row = base + (size_t)(CXY + U + r) * WW + CXY;
            _Float16* drow = sX + r * 416;
            for (int c2 = lane; c2 < 208; c2 += 64) {
                float2 v = *reinterpret_cast<const float2*>(row + 2 * c2);
                half2_t h;
                h[0] = (_Float16)v.x;
                h[1] = (_Float16)v.y;
                *reinterpret_cast<half2_t*>(drow + 2 * c2) = h;
            }
        }
    }
    __syncthreads();

    const int NJ = (wv == 0) ? 6 : 5;    // wave j-counts: 6,5,5,5 (21 total)
    const _Float16* tsh = (const _Float16*)(ws + TSHIFT_F);
    const _Float16* abase[6];
#pragma unroll
    for (int jj = 0; jj < 6; ++jj) {
        int j = wv + 4 * jj; if (j > 20) j = 20;   // clamped dummy for inactive slots
        abase[jj] = tsh + ((size_t)j * 384 + U + (lane & 15)) * 416 + (lane >> 4) * 8;
    }
    const _Float16* bbase = sX + (lane & 15) * 416 + (lane >> 4) * 8;

    f32x4 acc[6][3];
#pragma unroll
    for (int jj = 0; jj < 6; ++jj)
#pragma unroll
        for (int nt = 0; nt < 3; ++nt)
            acc[jj][nt] = (f32x4){0.f, 0.f, 0.f, 0.f};

#pragma unroll
    for (int kc = 0; kc < 13; ++kc) {
        f16x8 Bf[3];
#pragma unroll
        for (int nt = 0; nt < 3; ++nt)
            Bf[nt] = *reinterpret_cast<const f16x8*>(bbase + nt * (16 * 416) + kc * 32);
        f16x8 Af[6];
#pragma unroll
        for (int jj = 0; jj < 6; ++jj)
            Af[jj] = *reinterpret_cast<const f16x8*>(abase[jj] + kc * 32);
#pragma unroll
        for (int jj = 0; jj < 6; ++jj)
#pragma unroll
            for (int nt = 0; nt < 3; ++nt)
                acc[jj][nt] = __builtin_amdgcn_mfma_f32_16x16x32_f16(Af[jj], Bf[nt], acc[jj][nt], 0, 0, 0);
    }

    // ---- band extraction: D layout row=(lane>>4)*4+q, col=lane&15 (per n-tile) ----
    const int rbase = (lane >> 4) * 4;
    const int cbase = lane & 15;
#pragma unroll
    for (int jj = 0; jj < 6; ++jj) {
        if (jj < NJ) {
            int j = wv + 4 * jj;
#pragma unroll
            for (int nt = 0; nt < 3; ++nt)
#pragma unroll
                for (int q = 0; q < 4; ++q)
                    sD[wv][rbase + q][16 * nt + cbase] = acc[jj][nt][q];
            asm volatile("s_waitcnt lgkmcnt(0)" ::: "memory");
            float s = 0.f;
            if (lane < NL) {
#pragma unroll
                for (int row = 0; row < 16; ++row)
                    s += sD[wv][row][row + lane];    // i = w-u = lane; zero-T rows cover edges
            }
            asm volatile("s_waitcnt lgkmcnt(0)" ::: "memory");
            if (lane < NL)
                ws[CCPART2 + ((size_t)(b * NUT + Ut)) * 441 + lane * NL + j] = s;
        }
    }
}

// ---------------- K4: NCC + argmax (first-index ties) -> integer cell ----------------
__global__ __launch_bounds__(512) void k_ncc(float* __restrict__ ws) {
    int b = blockIdx.x, t = threadIdx.x;
    __shared__ float vbuf[512];
    __shared__ int   ibuf[512];
    float val = -1e30f;
    if (t < NL * NL) {
        float num = 0.f;
        for (int ut = 0; ut < NUT; ++ut)
            num += ws[CCPART2 + ((size_t)(b * NUT + ut)) * 441 + t];
        float ls  = ws[LOCALSUM + b * (NL * NL) + t];
        float lsq = ws[LOCALSQ  + b * (NL * NL) + t];
        float ivar = lsq - ls * ls * (1.0f / N_T) + EPSF;
        if (ivar < 0.f) ivar = 0.f;
        float den = sqrtf(ws[TSTATS + 1] * ivar);
        float ncc = num / den;
        if (ncc != ncc) ncc = 0.f;
        val = ncc;
    }
    vbuf[t] = val; ibuf[t] = t;
    __syncthreads();
    for (int off = 256; off; off >>= 1) {
        if (t < off) {
            float v1 = vbuf[t], v2 = vbuf[t + off];
            int   i1 = ibuf[t], i2 = ibuf[t + off];
            if (v2 > v1 || (v2 == v1 && i2 < i1)) { vbuf[t] = v2; ibuf[t] = i2; }
        }
        __syncthreads();
    }
    if (t == 0) {
        int am = ibuf[0];
        ws[SHIFTSI + 2 * b]     = (float)(am / NL);
        ws[SHIFTSI + 2 * b + 1] = (float)(am % NL);
    }
}

// ---------------- K4b: exact fp32 numerators at the 5 stencil points ----------------
__global__ __launch_bounds__(256) void k_exact1(const float* __restrict__ x,
                                                const float* __restrict__ tpl,
                                                float* __restrict__ ws) {
    const int b = blockIdx.x, k = blockIdx.y;
    const int sx = (int)ws[SHIFTSI + 2 * b];
    const int sy = (int)ws[SHIFTSI + 2 * b + 1];
    const int dxs[5] = {0, -1, 1, 0, 0};
    const int dys[5] = {0, 0, 0, -1, 1};
    const int px = min(max(sx + dxs[k], 0), NL - 1);
    const int py = min(max(sy + dys[k], 0), NL - 1);
    const float mu = ws[TSTATS];
    const int lane = threadIdx.x & 63, wv = threadIdx.x >> 6;
    float a = 0.f;
    for (int t = wv; t < TN; t += 4) {
        const float* trow = tpl + (TOFF + t) * WW + TOFF;
        const float* xrow = x + ((size_t)b * HH + (CXY + px + t)) * WW + CXY + py;
#pragma unroll
        for (int it = 0; it < 6; ++it) {
            int v = lane + it * 64;
            if (v < TN) a = fmaf(trow[v] - mu, xrow[v], a);
        }
    }
    for (int off = 32; off; off >>= 1) a += __shfl_down(a, off);
    __shared__ float part[4];
    if (lane == 0) part[wv] = a;
    __syncthreads();
    if (threadIdx.x == 0)
        ws[EXACTN + b * 5 + k] = part[0] + part[1] + part[2] + part[3];
}

// ---------------- K4c: subpixel shifts from exact numerators ----------------
__global__ __launch_bounds__(64) void k_sub(float* __restrict__ ws) {
    int b = threadIdx.x;
    if (b >= NB) return;
    int sx = (int)ws[SHIFTSI + 2 * b];
    int sy = (int)ws[SHIFTSI + 2 * b + 1];
    int lxm = max(sx - 1, 0), lxp = min(sx + 1, NL - 1);
    int lym = max(sy - 1, 0), lyp = min(sy + 1, NL - 1);
    float tvar = ws[TSTATS + 1];
    int cells[5] = { sx * NL + sy, lxm * NL + sy, lxp * NL + sy,
                     sx * NL + lym, sx * NL + lyp };
    float l[5];
    for (int k = 0; k < 5; ++k) {
        float num = ws[EXACTN + b * 5 + k];
        float ls  = ws[LOCALSUM + b * (NL * NL) + cells[k]];
        float lsq = ws[LOCALSQ  + b * (NL * NL) + cells[k]];
        float ivar = lsq - ls * ls * (1.0f / N_T) + EPSF;
        if (ivar < 0.f) ivar = 0.f;
        float ncc = num / sqrtf(tvar * ivar);
        if (ncc != ncc) ncc = 0.f;
        l[k] = logf(ncc);
    }
    float shx = -(float)(sx - 10) - (l[1] - l[2]) / (2.f * l[1] - 4.f * l[0] + 2.f * l[2]);
    float shy = -(float)(sy - 10) - (l[3] - l[4]) / (2.f * l[3] - 4.f * l[0] + 2.f * l[4]);
    ws[SHIFTS + 2 * b]     = shx;
    ws[SHIFTS + 2 * b + 1] = shy;
}

// ---------------- K5: bilinear warp, LDS-tiled (weights are const per batch) ----------------
__global__ __launch_bounds__(256) void k_warp(const float* __restrict__ x,
                                              const float* __restrict__ ws,
                                              float* __restrict__ out) {
    const int b = blockIdx.z;
    const int R = blockIdx.x * 64;     // output row tile
    const int C = blockIdx.y * 64;     // output col tile
    const float dy = ws[SHIFTS + 2 * b], dx = ws[SHIFTS + 2 * b + 1];
    const int rlo = (int)floorf((float)R - dy);
    const int clo = (int)floorf((float)C - dx);
    const float wr = ((float)R - dy) - (float)rlo;
    const float wc = ((float)C - dx) - (float)clo;
    __shared__ float sm[66][67];       // 66x66 staged tile, stride 67 (2-way free)
    const float* img = x + (size_t)b * (HH * WW);

    for (int k = threadIdx.x; k < 66 * 66; k += 256) {
        int kr = k / 66, kc = k - kr * 66;
        int ri = min(max(rlo + kr, 0), HH - 1);
        int ci = min(max(clo + kc, 0), WW - 1);
        sm[kr][kc] = img[ri * WW + ci];
    }
    __syncthreads();

    const int dr = threadIdx.x & 63;
    const int cq = threadIdx.x >> 6;     // 0..3
    const int r  = R + dr;
    const int r0 = rlo + dr;
    const float w00 = (1.f - wr) * (1.f - wc), w01 = (1.f - wr) * wc;
    const float w10 = wr * (1.f - wc),         w11 = wr * wc;
    const bool vr0 = (r0 >= 0) & (r0 < HH);
    const bool vr1 = (r0 + 1 >= 0) & (r0 + 1 < HH);
#pragma unroll
    for (int ci = 0; ci < 16; ++ci) {
        int dc = cq * 16 + ci;
        int c  = C + dc;
        int c0 = clo + dc;
        bool vc0 = (c0 >= 0) & (c0 < WW);
        bool vc1 = (c0 + 1 >= 0) & (c0 + 1 < WW);
        float v00 = (vr0 & vc0) ? sm[dr][dc]         : 0.f;
        float v01 = (vr0 & vc1) ? sm[dr][dc + 1]     : 0.f;
        float v10 = (vr1 & vc0) ? sm[dr + 1][dc]     : 0.f;
        float v11 = (vr1 & vc1) ? sm[dr + 1][dc + 1] : 0.f;
        float o = v00 * w00 + v01 * w01 + v10 * w10 + v11 * w11;
        out[(size_t)b * (HH * WW) + (size_t)c * HH + r] = o;
    }
}

extern "C" void kernel_launch(void* const* d_in, const int* in_sizes, int n_in,
                              void* d_out, int out_size, void* d_ws, size_t ws_size,
                              hipStream_t stream) {
    const float* x   = (const float*)d_in[0];
    const float* tpl = (const float*)d_in[1];
    float* out = (float*)d_out;
    float* ws  = (float*)d_ws;

    k_tstats1<<<TN, 128, 0, stream>>>(tpl, ws);
    k_tstats2<<<1, 512, 0, stream>>>(ws);
    k_tshift<<<dim3(384, NL), 256, 0, stream>>>(tpl, ws);
    k_rowsum<<<(NB * XN) / 4, 256, 0, stream>>>(x, ws);
    k_vert<<<NB, 512, 0, stream>>>(ws);
    k_ccm<<<dim3(NB, NUT), 256, 0, stream>>>(x, ws);
    k_ncc<<<NB, 512, 0, stream>>>(ws);
    k_exact1<<<dim3(NB, 5), 256, 0, stream>>>(x, tpl, ws);
    k_sub<<<1, 64, 0, stream>>>(ws);
    k_warp<<<dim3(8, 8, NB), dim3(256), 0, stream>>>(x, ws, out);
}

// Round 6
// 202.128 us; speedup vs baseline: 1.1108x; 1.1108x over previous
//
#include <hip/hip_runtime.h>
#include <math.h>

// Problem constants
#define HH 512
#define WW 512
#define NB 64
#define CXY 56          // crop offset of Xc in x
#define TOFF 66         // crop offset of tmpl in template (MS+C = 10+56)
#define TN 380          // template side
#define XN 400          // cropped image side
#define NL 21           // number of lags per dim (XN-TN+1)
#define N_T 144400.0f   // TN*TN
#define EPSF 1e-8f
#define NUT 24          // u-tiles of 16 rows (24*16 = 384 >= 380)
#define SXS 424         // padded sX row stride in halfs (848 B = 20 dwords mod 32)

// d_ws float offsets
#define TPART_S   0                    // 380
#define TPART_S2  384                  // 380
#define TSTATS    768                  // [0]=mu_t [1]=t_var
#define ROWSUM    1024                 // 64*400*21 = 537600
#define ROWSUMSQ  (ROWSUM + 537600)    // 538624
#define LOCALSUM  (ROWSUMSQ + 537600)  // 1076224 (64*441)
#define LOCALSQ   (LOCALSUM + 28224)   // 1104448
#define CCPART2   (LOCALSQ + 28224)    // 1132672 (64*24*441 = 677376)
#define SHIFTS    (CCPART2 + 677376)   // 1810048 (final float shifts)
#define SHIFTSI   (SHIFTS + 128)       // integer argmax cells
#define EXACTN    (SHIFTSI + 128)      // exact numerators, 5/batch
#define TSHIFT_F  (EXACTN + 384)       // 1810688; f16 buffer 21*384*416 halfs

typedef _Float16 half2_t __attribute__((ext_vector_type(2)));
typedef _Float16 f16x8 __attribute__((ext_vector_type(8)));
typedef float f32x4 __attribute__((ext_vector_type(4)));

// ---------------- K0a: per-template-row partial sums ----------------
__global__ __launch_bounds__(128) void k_tstats1(const float* __restrict__ tpl,
                                                 float* __restrict__ ws) {
    int u = blockIdx.x;            // 0..379
    int l = threadIdx.x;           // 128
    const float* row = tpl + (TOFF + u) * WW + TOFF;
    float s = 0.f, s2 = 0.f;
    for (int v = l; v < TN; v += 128) { float t = row[v]; s += t; s2 += t * t; }
    for (int off = 32; off; off >>= 1) { s += __shfl_down(s, off); s2 += __shfl_down(s2, off); }
    __shared__ float rs[2], rs2[2];
    int wid = l >> 6;
    if ((l & 63) == 0) { rs[wid] = s; rs2[wid] = s2; }
    __syncthreads();
    if (l == 0) { ws[TPART_S + u] = rs[0] + rs[1]; ws[TPART_S2 + u] = rs2[0] + rs2[1]; }
}

// ---------------- K0b: finalize template stats ----------------
__global__ __launch_bounds__(512) void k_tstats2(float* __restrict__ ws) {
    int l = threadIdx.x;           // 512
    float s  = (l < TN) ? ws[TPART_S + l]  : 0.f;
    float s2 = (l < TN) ? ws[TPART_S2 + l] : 0.f;
    for (int off = 32; off; off >>= 1) { s += __shfl_down(s, off); s2 += __shfl_down(s2, off); }
    __shared__ float rs[8], rs2[8];
    int wid = l >> 6;
    if ((l & 63) == 0) { rs[wid] = s; rs2[wid] = s2; }
    __syncthreads();
    if (l == 0) {
        float S = 0.f, S2 = 0.f;
        for (int k = 0; k < 8; ++k) { S += rs[k]; S2 += rs2[k]; }
        float mu = S / N_T;
        ws[TSTATS] = mu;
        ws[TSTATS + 1] = S2 - S * mu + EPSF;   // sum((T-mu)^2) + EPS
    }
}

// ---------------- K0c: build 21 shifted zero-mean f16 template copies ----------------
// T_j[u][v'] = (u<380 && 0 <= v'-j < 380) ? tpl[u][v'-j]-mu : 0, u in [0,384), v' in [0,416)
__global__ __launch_bounds__(256) void k_tshift(const float* __restrict__ tpl,
                                                float* __restrict__ ws) {
    int u = blockIdx.x;            // 0..383
    int j = blockIdx.y;            // 0..20
    float mu = ws[TSTATS];
    _Float16* dst = (_Float16*)(ws + TSHIFT_F) + ((size_t)j * 384 + u) * 416;
    for (int c = threadIdx.x; c < 416; c += 256) {
        float v = 0.f;
        int vs = c - j;
        if (u < TN && vs >= 0 && vs < TN) v = tpl[(TOFF + u) * WW + TOFF + vs] - mu;
        dst[c] = (_Float16)v;
    }
}

// ---------------- K1: per-row 380-wide sliding window sums ----------------
__global__ __launch_bounds__(256) void k_rowsum(const float* __restrict__ x,
                                                float* __restrict__ ws) {
    __shared__ float sm[4][XN];
    int wid = threadIdx.x >> 6, lane = threadIdx.x & 63;
    int row = blockIdx.x * 4 + wid;        // 0..25599
    int b = row / XN, p = row % XN;
    const float* xr = x + ((size_t)b * HH + (CXY + p)) * WW + CXY;
    float s = 0.f, s2 = 0.f;
    for (int v = lane; v < XN; v += 64) {
        float t = xr[v];
        sm[wid][v] = t;
        if (v < TN) { s += t; s2 += t * t; }
    }
    for (int off = 32; off; off >>= 1) { s += __shfl_down(s, off); s2 += __shfl_down(s2, off); }
    __syncthreads();
    if (lane == 0) {
        float* rs  = ws + ROWSUM   + (size_t)row * NL;
        float* rq  = ws + ROWSUMSQ + (size_t)row * NL;
        float w = s, w2 = s2;
        rs[0] = w; rq[0] = w2;
        for (int j = 1; j < NL; ++j) {
            float a = sm[wid][j - 1], bv = sm[wid][j + TN - 1];
            w  += bv - a;
            w2 += bv * bv - a * a;
            rs[j] = w; rq[j] = w2;
        }
    }
}

// ---------------- K2: vertical 380-tall sums -> localsum / localsum_sq ----------------
__global__ __launch_bounds__(512) void k_vert(float* __restrict__ ws) {
    int b = blockIdx.x, t = threadIdx.x;
    __shared__ float sm[XN * NL];   // 8400 floats = 33.6KB
    for (int k = t; k < XN * NL; k += 512) sm[k] = ws[ROWSUM + (size_t)b * (XN * NL) + k];
    __syncthreads();
    if (t < NL * NL) {
        float s = 0.f;
        for (int p = 0; p < TN; ++p) s += sm[t + p * NL];
        ws[LOCALSUM + b * (NL * NL) + t] = s;
    }
    __syncthreads();
    for (int k = t; k < XN * NL; k += 512) sm[k] = ws[ROWSUMSQ + (size_t)b * (XN * NL) + k];
    __syncthreads();
    if (t < NL * NL) {
        float s = 0.f;
        for (int p = 0; p < TN; ++p) s += sm[t + p * NL];
        ws[LOCALSQ + b * (NL * NL) + t] = s;
    }
}

// ---------------- K3: MFMA cross-correlation ----------------
// Block = (u-tile, batch).  GEMM per j: D[u][w] = sum_v' T_j[u][v'] X[w][v'].
// Grid x = Ut so each XCD serves only NUT/8 = 3 A-tiles (L2-resident).
// Explicit 2-deep double-buffer on A-fragments (global); X tile in LDS (padded).
__global__ __launch_bounds__(256, 3) void k_ccm(const float* __restrict__ x,
                                                float* __restrict__ ws) {
    const int Ut = blockIdx.x, b = blockIdx.y;
    const int U = Ut * 16;
    const int tid = threadIdx.x;
    const int lane = tid & 63, wv = tid >> 6;
    __shared__ __align__(16) _Float16 sX[48 * SXS];   // 40704 B
    __shared__ float sD[4][16][49];                   // 12544 B -> total 53248 (3 blocks/CU)

    // ---- stage X rows [U, U+48), cols [CXY, CXY+416) as f16 (all in-bounds) ----
    {
        const float* base = x + (size_t)b * (HH * WW);
        for (int rr = 0; rr < 12; ++rr) {
            int r = wv * 12 + rr;
            const float* row = base + (size_t)(CXY + U + r) * WW + CXY;
            _Float16* drow = sX + r * SXS;
            for (int c2 = lane; c2 < 208; c2 += 64) {
                float2 v = *reinterpret_cast<const float2*>(row + 2 * c2);
                half2_t h;
                h[0] = (_Float16)v.x;
                h[1] = (_Float16)v.y;
                *reinterpret_cast<half2_t*>(drow + 2 * c2) = h;
            }
        }
    }
    __syncthreads();

    const int NJ = (wv == 0) ? 6 : 5;    // wave j-counts: 6,5,5,5 (21 total)
    const _Float16* tsh = (const _Float16*)(ws + TSHIFT_F);
    const _Float16* abase[6];
#pragma unroll
    for (int jj = 0; jj < 6; ++jj) {
        int j = wv + 4 * jj; if (j > 20) j = 20;   // clamp keeps addr in-bounds; unused if jj>=NJ
        abase[jj] = tsh + ((size_t)j * 384 + U + (lane & 15)) * 416 + (lane >> 4) * 8;
    }
    const _Float16* bbase = sX + (lane & 15) * SXS + (lane >> 4) * 8;

    f32x4 acc[6][3];
#pragma unroll
    for (int jj = 0; jj < 6; ++jj)
#pragma unroll
        for (int nt = 0; nt < 3; ++nt)
            acc[jj][nt] = (f32x4){0.f, 0.f, 0.f, 0.f};

    f16x8 Ab[2][6];
#pragma unroll
    for (int jj = 0; jj < 6; ++jj)
        if (jj < NJ) Ab[0][jj] = *reinterpret_cast<const f16x8*>(abase[jj]);

#pragma unroll
    for (int kc = 0; kc < 13; ++kc) {
        // prefetch next kc's A-fragments (independent of this kc's MFMAs)
        if (kc < 12) {
#pragma unroll
            for (int jj = 0; jj < 6; ++jj)
                if (jj < NJ)
                    Ab[(kc + 1) & 1][jj] =
                        *reinterpret_cast<const f16x8*>(abase[jj] + (kc + 1) * 32);
        }
        f16x8 Bf[3];
#pragma unroll
        for (int nt = 0; nt < 3; ++nt)
            Bf[nt] = *reinterpret_cast<const f16x8*>(bbase + nt * (16 * SXS) + kc * 32);
        __builtin_amdgcn_s_setprio(1);
#pragma unroll
        for (int jj = 0; jj < 6; ++jj)
            if (jj < NJ)
#pragma unroll
                for (int nt = 0; nt < 3; ++nt)
                    acc[jj][nt] = __builtin_amdgcn_mfma_f32_16x16x32_f16(
                        Ab[kc & 1][jj], Bf[nt], acc[jj][nt], 0, 0, 0);
        __builtin_amdgcn_s_setprio(0);
    }

    // ---- band extraction: D layout row=(lane>>4)*4+q, col=lane&15 (per n-tile) ----
    const int rbase = (lane >> 4) * 4;
    const int cbase = lane & 15;
#pragma unroll
    for (int jj = 0; jj < 6; ++jj) {
        if (jj < NJ) {
            int j = wv + 4 * jj;
#pragma unroll
            for (int nt = 0; nt < 3; ++nt)
#pragma unroll
                for (int q = 0; q < 4; ++q)
                    sD[wv][rbase + q][16 * nt + cbase] = acc[jj][nt][q];
            asm volatile("s_waitcnt lgkmcnt(0)" ::: "memory");
            float s = 0.f;
            if (lane < NL) {
#pragma unroll
                for (int row = 0; row < 16; ++row)
                    s += sD[wv][row][row + lane];    // i = w-u = lane; zero-T rows cover edges
            }
            asm volatile("s_waitcnt lgkmcnt(0)" ::: "memory");
            if (lane < NL)
                ws[CCPART2 + ((size_t)(b * NUT + Ut)) * 441 + lane * NL + j] = s;
        }
    }
}

// ---------------- K4: NCC + argmax (first-index ties) -> integer cell ----------------
__global__ __launch_bounds__(512) void k_ncc(float* __restrict__ ws) {
    int b = blockIdx.x, t = threadIdx.x;
    __shared__ float vbuf[512];
    __shared__ int   ibuf[512];
    float val = -1e30f;
    if (t < NL * NL) {
        float num = 0.f;
        for (int ut = 0; ut < NUT; ++ut)
            num += ws[CCPART2 + ((size_t)(b * NUT + ut)) * 441 + t];
        float ls  = ws[LOCALSUM + b * (NL * NL) + t];
        float lsq = ws[LOCALSQ  + b * (NL * NL) + t];
        float ivar = lsq - ls * ls * (1.0f / N_T) + EPSF;
        if (ivar < 0.f) ivar = 0.f;
        float den = sqrtf(ws[TSTATS + 1] * ivar);
        float ncc = num / den;
        if (ncc != ncc) ncc = 0.f;
        val = ncc;
    }
    vbuf[t] = val; ibuf[t] = t;
    __syncthreads();
    for (int off = 256; off; off >>= 1) {
        if (t < off) {
            float v1 = vbuf[t], v2 = vbuf[t + off];
            int   i1 = ibuf[t], i2 = ibuf[t + off];
            if (v2 > v1 || (v2 == v1 && i2 < i1)) { vbuf[t] = v2; ibuf[t] = i2; }
        }
        __syncthreads();
    }
    if (t == 0) {
        int am = ibuf[0];
        ws[SHIFTSI + 2 * b]     = (float)(am / NL);
        ws[SHIFTSI + 2 * b + 1] = (float)(am % NL);
    }
}

// ---------------- K4b: exact fp32 numerators at the 5 stencil points ----------------
__global__ __launch_bounds__(256) void k_exact1(const float* __restrict__ x,
                                                const float* __restrict__ tpl,
                                                float* __restrict__ ws) {
    const int b = blockIdx.x, k = blockIdx.y;
    const int sx = (int)ws[SHIFTSI + 2 * b];
    const int sy = (int)ws[SHIFTSI + 2 * b + 1];
    const int dxs[5] = {0, -1, 1, 0, 0};
    const int dys[5] = {0, 0, 0, -1, 1};
    const int px = min(max(sx + dxs[k], 0), NL - 1);
    const int py = min(max(sy + dys[k], 0), NL - 1);
    const float mu = ws[TSTATS];
    const int lane = threadIdx.x & 63, wv = threadIdx.x >> 6;
    float a = 0.f;
    for (int t = wv; t < TN; t += 4) {
        const float* trow = tpl + (TOFF + t) * WW + TOFF;
        const float* xrow = x + ((size_t)b * HH + (CXY + px + t)) * WW + CXY + py;
#pragma unroll
        for (int it = 0; it < 6; ++it) {
            int v = lane + it * 64;
            if (v < TN) a = fmaf(trow[v] - mu, xrow[v], a);
        }
    }
    for (int off = 32; off; off >>= 1) a += __shfl_down(a, off);
    __shared__ float part[4];
    if (lane == 0) part[wv] = a;
    __syncthreads();
    if (threadIdx.x == 0)
        ws[EXACTN + b * 5 + k] = part[0] + part[1] + part[2] + part[3];
}

// ---------------- K4c: subpixel shifts from exact numerators ----------------
__global__ __launch_bounds__(64) void k_sub(float* __restrict__ ws) {
    int b = threadIdx.x;
    if (b >= NB) return;
    int sx = (int)ws[SHIFTSI + 2 * b];
    int sy = (int)ws[SHIFTSI + 2 * b + 1];
    int lxm = max(sx - 1, 0), lxp = min(sx + 1, NL - 1);
    int lym = max(sy - 1, 0), lyp = min(sy + 1, NL - 1);
    float tvar = ws[TSTATS + 1];
    int cells[5] = { sx * NL + sy, lxm * NL + sy, lxp * NL + sy,
                     sx * NL + lym, sx * NL + lyp };
    float l[5];
    for (int k = 0; k < 5; ++k) {
        float num = ws[EXACTN + b * 5 + k];
        float ls  = ws[LOCALSUM + b * (NL * NL) + cells[k]];
        float lsq = ws[LOCALSQ  + b * (NL * NL) + cells[k]];
        float ivar = lsq - ls * ls * (1.0f / N_T) + EPSF;
        if (ivar < 0.f) ivar = 0.f;
        float ncc = num / sqrtf(tvar * ivar);
        if (ncc != ncc) ncc = 0.f;
        l[k] = logf(ncc);
    }
    float shx = -(float)(sx - 10) - (l[1] - l[2]) / (2.f * l[1] - 4.f * l[0] + 2.f * l[2]);
    float shy = -(float)(sy - 10) - (l[3] - l[4]) / (2.f * l[3] - 4.f * l[0] + 2.f * l[4]);
    ws[SHIFTS + 2 * b]     = shx;
    ws[SHIFTS + 2 * b + 1] = shy;
}

// ---------------- K5: bilinear warp, LDS-tiled (weights are const per batch) ----------------
__global__ __launch_bounds__(256) void k_warp(const float* __restrict__ x,
                                              const float* __restrict__ ws,
                                              float* __restrict__ out) {
    const int b = blockIdx.z;
    const int R = blockIdx.x * 64;     // output row tile
    const int C = blockIdx.y * 64;     // output col tile
    const float dy = ws[SHIFTS + 2 * b], dx = ws[SHIFTS + 2 * b + 1];
    const int rlo = (int)floorf((float)R - dy);
    const int clo = (int)floorf((float)C - dx);
    const float wr = ((float)R - dy) - (float)rlo;
    const float wc = ((float)C - dx) - (float)clo;
    __shared__ float sm[66][67];       // 66x66 staged tile, stride 67 (2-way free)
    const float* img = x + (size_t)b * (HH * WW);

    for (int k = threadIdx.x; k < 66 * 66; k += 256) {
        int kr = k / 66, kc = k - kr * 66;
        int ri = min(max(rlo + kr, 0), HH - 1);
        int ci = min(max(clo + kc, 0), WW - 1);
        sm[kr][kc] = img[ri * WW + ci];
    }
    __syncthreads();

    const int dr = threadIdx.x & 63;
    const int cq = threadIdx.x >> 6;     // 0..3
    const int r  = R + dr;
    const int r0 = rlo + dr;
    const float w00 = (1.f - wr) * (1.f - wc), w01 = (1.f - wr) * wc;
    const float w10 = wr * (1.f - wc),         w11 = wr * wc;
    const bool vr0 = (r0 >= 0) & (r0 < HH);
    const bool vr1 = (r0 + 1 >= 0) & (r0 + 1 < HH);
#pragma unroll
    for (int ci = 0; ci < 16; ++ci) {
        int dc = cq * 16 + ci;
        int c  = C + dc;
        int c0 = clo + dc;
        bool vc0 = (c0 >= 0) & (c0 < WW);
        bool vc1 = (c0 + 1 >= 0) & (c0 + 1 < WW);
        float v00 = (vr0 & vc0) ? sm[dr][dc]         : 0.f;
        float v01 = (vr0 & vc1) ? sm[dr][dc + 1]     : 0.f;
        float v10 = (vr1 & vc0) ? sm[dr + 1][dc]     : 0.f;
        float v11 = (vr1 & vc1) ? sm[dr + 1][dc + 1] : 0.f;
        float o = v00 * w00 + v01 * w01 + v10 * w10 + v11 * w11;
        out[(size_t)b * (HH * WW) + (size_t)c * HH + r] = o;
    }
}

extern "C" void kernel_launch(void* const* d_in, const int* in_sizes, int n_in,
                              void* d_out, int out_size, void* d_ws, size_t ws_size,
                              hipStream_t stream) {
    const float* x   = (const float*)d_in[0];
    const float* tpl = (const float*)d_in[1];
    float* out = (float*)d_out;
    float* ws  = (float*)d_ws;

    k_tstats1<<<TN, 128, 0, stream>>>(tpl, ws);
    k_tstats2<<<1, 512, 0, stream>>>(ws);
    k_tshift<<<dim3(384, NL), 256, 0, stream>>>(tpl, ws);
    k_rowsum<<<(NB * XN) / 4, 256, 0, stream>>>(x, ws);
    k_vert<<<NB, 512, 0, stream>>>(ws);
    k_ccm<<<dim3(NUT, NB), 256, 0, stream>>>(x, ws);
    k_ncc<<<NB, 512, 0, stream>>>(ws);
    k_exact1<<<dim3(NB, 5), 256, 0, stream>>>(x, tpl, ws);
    k_sub<<<1, 64, 0, stream>>>(ws);
    k_warp<<<dim3(8, 8, NB), dim3(256), 0, stream>>>(x, ws, out);
}